// Round 1
// baseline (93.280 us; speedup 1.0000x reference)
//
#include <hip/hip_runtime.h>

// Problem: A=1, B=32, M=32, H=1024, E=8, N=1024 (all fp32)
// out[b,e] = mask[b,e] * sum_h (sum_m hidden[b,m,h]) * (sum_n weight[e,h,n])
//
// Fused single-kernel design:
//   grid = 512 blocks = 8 e-slices x 64 h-chunks (CHUNK=16 h per block).
//   Each block:
//     A) wsum[h'] for its 16 weight rows (e, h0..h0+15)  -- 64 KB coalesced float4
//     B) hsum[b,h'] for all 32 b over its h-chunk         -- 64 KB (8x redundant
//        across e-partners; hidden is 4 MB, L3-resident; e-partners are 64 apart
//        in blockIdx => same XCD under default round-robin => shared L2 lines)
//     C) partial[b] = sum_h' hsum*wsum, then atomicAdd(out[b,e], partial*mask)
//   out is zeroed by a 1 KB memset node (replaces the old dot-kernel node).
// No ws usage, no producer->consumer kernel boundary, no full-grid drain before
// the dot work -- the tail is overlapped with streaming.

#define Bdim 32
#define Mdim 32
#define Hdim 1024
#define Edim 8
#define Ndim 1024
#define CHUNK 16

__global__ __launch_bounds__(256) void fused_kernel(
    const float* __restrict__ hidden,    // (B,M,H)
    const float* __restrict__ weight,    // (E,H,N)
    const float* __restrict__ sparsity,  // (B,E) flat
    float* __restrict__ out)             // (B,E) flat, pre-zeroed
{
    __shared__ float wsum_l[CHUNK];
    __shared__ float hsum_l[Bdim][CHUNK + 1];   // +1 pad: conflict-free column read

    const int e  = blockIdx.x >> 6;   // 0..7
    const int hc = blockIdx.x & 63;   // 0..63
    const int h0 = hc * CHUNK;

    // ---- A) weight row sums: wave w handles rows h0+w*4 .. h0+w*4+3
    {
        const int wave = threadIdx.x >> 6;
        const int lane = threadIdx.x & 63;
        const float4* w4 = reinterpret_cast<const float4*>(weight);
        #pragma unroll
        for (int r = 0; r < 4; ++r) {
            const int row = e * Hdim + h0 + wave * 4 + r;   // <= 8191
            float s = 0.f;
            #pragma unroll
            for (int j = 0; j < 4; ++j) {
                float4 v = w4[row * (Ndim / 4) + j * 64 + lane];
                s += (v.x + v.y) + (v.z + v.w);
            }
            #pragma unroll
            for (int off = 32; off > 0; off >>= 1)
                s += __shfl_xor(s, off, 64);
            if (lane == 0) wsum_l[wave * 4 + r] = s;
        }
    }

    // ---- B) hidden M-sums for this h-chunk: thread t -> h'=t&15, q=t>>4,
    //         b = q and q+16. Lanes 0-15 read 64 B contiguous per m-step.
    {
        const int hp = threadIdx.x & 15;
        const int q  = threadIdx.x >> 4;
        #pragma unroll
        for (int b2 = 0; b2 < 2; ++b2) {
            const int b = q + 16 * b2;
            const float* p = hidden + b * (Mdim * Hdim) + h0 + hp;
            float s = 0.f;
            #pragma unroll
            for (int m = 0; m < Mdim; ++m) s += p[m * Hdim];
            hsum_l[b][hp] = s;
        }
    }

    __syncthreads();

    // ---- C) per-block partial dot + one atomic per (b,e)
    if (threadIdx.x < Bdim) {
        const int b = threadIdx.x;
        float s = 0.f;
        #pragma unroll
        for (int h = 0; h < CHUNK; ++h)
            s += hsum_l[b][h] * wsum_l[h];
        const int o = b * Edim + e;
        atomicAdd(&out[o], s * sparsity[o]);
    }
}

extern "C" void kernel_launch(void* const* d_in, const int* in_sizes, int n_in,
                              void* d_out, int out_size, void* d_ws, size_t ws_size,
                              hipStream_t stream) {
    const float* hidden   = (const float*)d_in[0];  // (1,32,32,1024)
    const float* sparsity = (const float*)d_in[1];  // (1,32,1,8)
    const float* weight   = (const float*)d_in[2];  // (1,8,1024,1024)
    float* out = (float*)d_out;                     // (1,32,8)

    hipMemsetAsync(out, 0, Bdim * Edim * sizeof(float), stream);
    fused_kernel<<<Edim * (Hdim / CHUNK), 256, 0, stream>>>(hidden, weight, sparsity, out);
}

// Round 2
// 80.643 us; speedup vs baseline: 1.1567x; 1.1567x over previous
//
#include <hip/hip_runtime.h>

// Problem: A=1, B=32, M=32, H=1024, E=8, N=1024 (all fp32)
// out[b,e] = mask[b,e] * sum_h (sum_m hidden[b,m,h]) * (sum_n weight[e,h,n])
//
// Two-kernel structure (round-0 verified best), rebalanced:
//   Kernel A: 512 blocks == 2 blocks/CU exactly, 72 KB streamed per block:
//     - all 4 waves: 16 weight rows (e*H+h), float4, wave-shuffle row sums
//     - wave 0 only: 16 float4 hidden columns, M-reduction, 4 lanes/column
//   Kernel B: 256 waves, one per (b,e), float4 dot of hsum[b,:].wsum[e,:].
//
// ws layout (floats): [0, E*H)          wsum  (8192)
//                     [E*H, E*H + B*H)  hsum  (32768)

#define Bdim 32
#define Mdim 32
#define Hdim 1024
#define Edim 8
#define Ndim 1024

__global__ __launch_bounds__(256) void reduce_kernel(
    const float* __restrict__ hidden,   // (B,M,H)
    const float* __restrict__ weight,   // (E,H,N)
    float* __restrict__ ws)
{
    const int wave = threadIdx.x >> 6;
    const int lane = threadIdx.x & 63;

    // ---- Phase A: weight row sums. Block owns rows [blockIdx*16, +16),
    //      wave w owns 4 of them. 64 KB/block, fully coalesced float4.
    {
        const float4* w4 = reinterpret_cast<const float4*>(weight);
        #pragma unroll
        for (int r = 0; r < 4; ++r) {
            const int row = blockIdx.x * 16 + wave * 4 + r;   // row = e*H + h
            float s = 0.f;
            #pragma unroll
            for (int j = 0; j < 4; ++j) {
                float4 v = w4[row * (Ndim / 4) + j * 64 + lane];
                s += (v.x + v.y) + (v.z + v.w);
            }
            #pragma unroll
            for (int off = 32; off > 0; off >>= 1)
                s += __shfl_xor(s, off, 64);
            if (lane == 0) ws[row] = s;
        }
    }

    // ---- Phase B: hidden M-sums as float4 columns. Block owns 16 f4-columns
    //      (c = b*256 + h4). Wave 0 only: 4 lanes per column, 8 m-steps each,
    //      combined with 2 shfl_xor. 8 KB/block. Lanes 0-15 read 256 B
    //      contiguous per m-step (16 adjacent h4).
    if (threadIdx.x < 64) {
        const int c  = blockIdx.x * 16 + (lane & 15);   // 0..8191
        const int mg = lane >> 4;                        // 0..3
        const int b  = c >> 8;                           // Hdim/4 = 256 f4/row
        const int h4 = c & 255;
        const float4* hp = reinterpret_cast<const float4*>(hidden)
                         + b * (Mdim * Hdim / 4) + h4;
        float4 s = {0.f, 0.f, 0.f, 0.f};
        #pragma unroll
        for (int m = 0; m < 8; ++m) {
            float4 v = hp[(mg * 8 + m) * (Hdim / 4)];
            s.x += v.x; s.y += v.y; s.z += v.z; s.w += v.w;
        }
        #pragma unroll
        for (int off = 16; off <= 32; off <<= 1) {
            s.x += __shfl_xor(s.x, off, 64);
            s.y += __shfl_xor(s.y, off, 64);
            s.z += __shfl_xor(s.z, off, 64);
            s.w += __shfl_xor(s.w, off, 64);
        }
        if (mg == 0)
            reinterpret_cast<float4*>(ws + Edim * Hdim)[c] = s;
    }
}

// Kernel B: 256 waves, one per (b,e); float4 dot over h of hsum[b,:]*wsum[e,:],
// masked by sparsity[b,e]. Reads 2 MB total, L2/L3-resident.
__global__ __launch_bounds__(256) void dot_kernel(
    const float* __restrict__ ws,
    const float* __restrict__ sparsity,  // (B,E) flat
    float* __restrict__ out)             // (B,E) flat
{
    const int o = blockIdx.x * 4 + (threadIdx.x >> 6);   // b*E + e, 0..255
    const int lane = threadIdx.x & 63;
    const int b = o >> 3;
    const int e = o & 7;
    const float4* hs = reinterpret_cast<const float4*>(ws + Edim * Hdim + b * Hdim);
    const float4* wv = reinterpret_cast<const float4*>(ws + e * Hdim);
    float s = 0.f;
    #pragma unroll
    for (int j = 0; j < 4; ++j) {
        float4 h4 = hs[j * 64 + lane];
        float4 w4 = wv[j * 64 + lane];
        s += h4.x * w4.x + h4.y * w4.y + h4.z * w4.z + h4.w * w4.w;
    }
    #pragma unroll
    for (int off = 32; off > 0; off >>= 1)
        s += __shfl_xor(s, off, 64);
    if (lane == 0) out[o] = s * sparsity[o];
}

extern "C" void kernel_launch(void* const* d_in, const int* in_sizes, int n_in,
                              void* d_out, int out_size, void* d_ws, size_t ws_size,
                              hipStream_t stream) {
    const float* hidden   = (const float*)d_in[0];  // (1,32,32,1024)
    const float* sparsity = (const float*)d_in[1];  // (1,32,1,8)
    const float* weight   = (const float*)d_in[2];  // (1,8,1024,1024)
    float* out = (float*)d_out;                     // (1,32,8)
    float* ws  = (float*)d_ws;

    reduce_kernel<<<512, 256, 0, stream>>>(hidden, weight, ws);
    dot_kernel<<<64, 256, 0, stream>>>(ws, sparsity, out);
}